// Round 1
// baseline (946.458 us; speedup 1.0000x reference)
//
#include <hip/hip_runtime.h>
#include <hip/hip_bf16.h>

#define NB 16
#define NP 4096
#define DDIM 768
#define MTOT (NB*NP)     // 65536
#define N1 1536
#define BM 128
#define BN 128
#define BK 64
#define LDT 72           // padded LDS row stride (bf16 elems): +8 kills 16-way bank conflict
#define SCALEF 0.015625f // 4096^-0.5
#define LNEPS 1e-5f

typedef __attribute__((ext_vector_type(8))) short bf16x8;
typedef __attribute__((ext_vector_type(4))) float f32x4;
typedef __attribute__((ext_vector_type(4))) unsigned int u32x4;

__device__ __forceinline__ unsigned short f2b(float f){
  union { float f; unsigned int u; } v; v.f = f;
  unsigned int u = v.u;
  unsigned int r = (u + 0x7FFFu + ((u >> 16) & 1u)) >> 16; // RNE
  return (unsigned short)r;
}
__device__ __forceinline__ unsigned int pack2(float a, float b){
  return (unsigned int)f2b(a) | ((unsigned int)f2b(b) << 16);
}
__device__ __forceinline__ float b2f(unsigned short h){
  union { unsigned int u; float f; } v; v.u = ((unsigned int)h) << 16;
  return v.f;
}
__device__ __forceinline__ float b2f_lo(unsigned int u){
  union { unsigned int x; float f; } v; v.x = u << 16; return v.f;
}
__device__ __forceinline__ float b2f_hi(unsigned int u){
  union { unsigned int x; float f; } v; v.x = u & 0xFFFF0000u; return v.f;
}

// ---------------- prep: Wt1[n][k] = [wq|wk]^T (bf16), Wt2[n][k] = w_proj^T (bf16)
__global__ __launch_bounds__(256) void prep_w(const float* __restrict__ wq,
                                              const float* __restrict__ wk,
                                              const float* __restrict__ wp,
                                              unsigned short* __restrict__ wt1,
                                              unsigned short* __restrict__ wt2){
  int idx = blockIdx.x * 256 + threadIdx.x;
  const int tot1 = N1 * DDIM;
  if (idx < tot1){
    int n = idx / DDIM, k = idx % DDIM;
    float v = (n < DDIM) ? wq[k * DDIM + n] : wk[k * DDIM + (n - DDIM)];
    wt1[idx] = f2b(v);
  }
  int idx2 = idx - tot1;
  if (idx2 >= 0 && idx2 < DDIM * DDIM){
    int n = idx2 / DDIM, k = idx2 % DDIM;
    wt2[idx2] = f2b(wp[k * DDIM + n]);
  }
}

// ---------------- GEMM1: [q|k] = x @ [wq|wk] + bias. Writes k (bf16), and
// per-block column partials: qw (w_g-weighted row sum of q), qs (row sum of q),
// ks (row sum of k). q itself is never stored.
__global__ __launch_bounds__(256) void gemm_qk(
    const float* __restrict__ x, const unsigned short* __restrict__ wt1,
    const float* __restrict__ bq, const float* __restrict__ bk,
    const float* __restrict__ w_g,
    unsigned short* __restrict__ kout,
    float* __restrict__ qwp, float* __restrict__ qsp, float* __restrict__ ksp)
{
  __shared__ unsigned short A_lds[BM][LDT];
  __shared__ unsigned short B_lds[BN][LDT];
  __shared__ float wg_lds[BM];
  __shared__ float part0[BM][8];
  __shared__ float part1[BM][8];

  // XCD-chunked swizzle (gridDim.x % 8 == 0): consecutive logical tiles on same XCD
  int bid = blockIdx.x;
  int swz = (bid & 7) * ((int)gridDim.x >> 3) + (bid >> 3);
  const int NBN = N1 / BN; // 12, fastest-varying so A-panel is shared in L2
  int bn = swz % NBN, bm = swz / NBN;
  int m0 = bm * BM, n0 = bn * BN;
  int t = threadIdx.x;
  int lane = t & 63, wave = t >> 6;
  int wm = wave >> 1, wn = wave & 1;
  int lr = lane & 15, lh = lane >> 4;

  if (t < BM) wg_lds[t] = w_g[(m0 & (NP - 1)) + t];

  f32x4 acc[4][4] = {};
  int c8 = t & 7, rr = t >> 3;

  for (int ks = 0; ks < DDIM / BK; ++ks){
    int k0 = ks * BK;
    // stage A: x f32 -> bf16 LDS
    #pragma unroll
    for (int s = 0; s < 4; ++s){
      int row = rr + s * 32;
      const float4* src = reinterpret_cast<const float4*>(x + (size_t)(m0 + row) * DDIM + k0 + c8 * 8);
      float4 v0 = src[0], v1 = src[1];
      u32x4 w;
      w[0] = pack2(v0.x, v0.y); w[1] = pack2(v0.z, v0.w);
      w[2] = pack2(v1.x, v1.y); w[3] = pack2(v1.z, v1.w);
      *reinterpret_cast<u32x4*>(&A_lds[row][c8 * 8]) = w;
    }
    // stage B: pre-transposed bf16 weights
    #pragma unroll
    for (int s = 0; s < 4; ++s){
      int row = rr + s * 32;
      u32x4 w = *reinterpret_cast<const u32x4*>(wt1 + (size_t)(n0 + row) * DDIM + k0 + c8 * 8);
      *reinterpret_cast<u32x4*>(&B_lds[row][c8 * 8]) = w;
    }
    __syncthreads();
    #pragma unroll
    for (int kk = 0; kk < 2; ++kk){
      bf16x8 af[4], bfr[4];
      #pragma unroll
      for (int i = 0; i < 4; ++i)
        af[i] = *reinterpret_cast<const bf16x8*>(&A_lds[wm * 64 + i * 16 + lr][kk * 32 + lh * 8]);
      #pragma unroll
      for (int i = 0; i < 4; ++i)
        bfr[i] = *reinterpret_cast<const bf16x8*>(&B_lds[wn * 64 + i * 16 + lr][kk * 32 + lh * 8]);
      #pragma unroll
      for (int i = 0; i < 4; ++i)
        #pragma unroll
        for (int j = 0; j < 4; ++j)
          acc[i][j] = __builtin_amdgcn_mfma_f32_16x16x32_bf16(af[i], bfr[j], acc[i][j], 0, 0, 0);
    }
    __syncthreads();
  }

  bool is_q = (n0 < DDIM);
  int b = m0 / NP;
  int mc = (m0 % NP) / BM;
  float r0a[4], r1a[4];
  #pragma unroll
  for (int nf = 0; nf < 4; ++nf){
    int colb = wn * 64 + nf * 16 + lr;
    int col = n0 + colb;
    float bias = is_q ? bq[col] : bk[col - DDIM];
    float s0 = 0.f, s1 = 0.f;
    #pragma unroll
    for (int mf = 0; mf < 4; ++mf){
      #pragma unroll
      for (int r = 0; r < 4; ++r){
        int rowb = wm * 64 + mf * 16 + lh * 4 + r;
        float val = acc[mf][nf][r] + bias;   // C/D: col=lane&15, row=(lane>>4)*4+r
        if (is_q){
          s0 += wg_lds[rowb] * val;
          s1 += val;
        } else {
          s0 += val;
          kout[(size_t)(m0 + rowb) * DDIM + (col - DDIM)] = f2b(val);
        }
      }
    }
    r0a[nf] = s0; r1a[nf] = s1;
  }
  int slot = wm * 4 + lh;
  #pragma unroll
  for (int nf = 0; nf < 4; ++nf){
    int colb = wn * 64 + nf * 16 + lr;
    part0[colb][slot] = r0a[nf];
    part1[colb][slot] = r1a[nf];
  }
  __syncthreads();
  if (t < BM){
    float s0 = 0.f, s1 = 0.f;
    #pragma unroll
    for (int i = 0; i < 8; ++i){ s0 += part0[t][i]; s1 += part1[t][i]; }
    size_t base = ((size_t)b * 32 + mc) * DDIM;
    if (is_q){
      qwp[base + n0 + t] = s0;
      qsp[base + n0 + t] = s1;
    } else {
      ksp[base + (n0 - DDIM) + t] = s0;
    }
  }
}

// ---------------- combine: per batch — reduce partials, softmax over d,
// gelu/fc2/sigmoid gating chain, g = A * ksum * dv
__global__ __launch_bounds__(256) void combine(
    const float* __restrict__ qwp, const float* __restrict__ qsp, const float* __restrict__ ksp,
    const float* __restrict__ w_fc, const float* __restrict__ b_fc,
    const float* __restrict__ w_fc2, const float* __restrict__ b_fc2,
    float* __restrict__ g)
{
  __shared__ float smA[DDIM];
  __shared__ float smQM[DDIM];
  __shared__ float smKS[DDIM];
  __shared__ float tmat[12][DDIM];
  __shared__ float red[256];
  __shared__ float wbar[12];
  __shared__ float bbar;
  int b = blockIdx.x, t = threadIdx.x;

  for (int col = t; col < DDIM; col += 256){
    float s0 = 0.f, s1 = 0.f, s2 = 0.f;
    for (int mc = 0; mc < 32; ++mc){
      size_t base = ((size_t)b * 32 + mc) * DDIM + col;
      s0 += qwp[base]; s1 += qsp[base]; s2 += ksp[base];
    }
    smA[col] = s0 * SCALEF;
    smQM[col] = s1 * (1.0f / NP);
    smKS[col] = s2;
  }
  __syncthreads();
  // softmax over channel dim
  float lmax = -1e30f;
  for (int col = t; col < DDIM; col += 256) lmax = fmaxf(lmax, smA[col]);
  red[t] = lmax; __syncthreads();
  for (int off = 128; off; off >>= 1){
    if (t < off) red[t] = fmaxf(red[t], red[t + off]);
    __syncthreads();
  }
  float mx = red[0];
  __syncthreads();
  float lsum = 0.f;
  for (int col = t; col < DDIM; col += 256){
    float e = __expf(smA[col] - mx);
    smA[col] = e; lsum += e;
  }
  red[t] = lsum; __syncthreads();
  for (int off = 128; off; off >>= 1){
    if (t < off) red[t] += red[t + off];
    __syncthreads();
  }
  float inv = 1.0f / red[0];
  for (int col = t; col < DDIM; col += 256) smA[col] *= inv;

  if (t < 12){
    float s = 0.f;
    for (int j = 0; j < 12; ++j) s += w_fc2[t * 12 + j];
    wbar[t] = s * (1.0f / 12.0f);
  }
  if (t == 12){
    float s = 0.f;
    for (int j = 0; j < 12; ++j) s += b_fc2[j];
    bbar = s * (1.0f / 12.0f);
  }
  __syncthreads();
  // t[h][j] = gelu(qmean[h*64: ] @ w_fc + b_fc), exact gelu
  for (int idx = t; idx < 12 * DDIM; idx += 256){
    int h = idx / DDIM, j = idx % DDIM;
    float s = b_fc[j];
    const float* qm = &smQM[h * 64];
    #pragma unroll 4
    for (int i = 0; i < 64; ++i) s += qm[i] * w_fc[i * DDIM + j];
    tmat[h][j] = 0.5f * s * (1.0f + erff(s * 0.70710678118654752f));
  }
  __syncthreads();
  for (int p = t; p < DDIM; p += 256){
    float s = bbar;
    #pragma unroll
    for (int m = 0; m < 12; ++m){
      int f = p * 12 + m;                 // torch-style reshape (b,12,768)->(b,768,12)
      s += tmat[f / DDIM][f % DDIM] * wbar[m];
    }
    float dv = 1.0f / (1.0f + __expf(-s));
    g[(size_t)b * DDIM + p] = smA[p] * smKS[p] * dv;
  }
}

// ---------------- GEMM2: out = (g⊙k) @ w_proj + b_proj + layernorm(k)
__global__ __launch_bounds__(256) void gemm_out(
    const unsigned short* __restrict__ kin, const unsigned short* __restrict__ wt2,
    const float* __restrict__ g, const float* __restrict__ bp,
    const float* __restrict__ gamma, const float* __restrict__ beta,
    float* __restrict__ out)
{
  __shared__ unsigned short A_lds[BM][LDT];
  __shared__ unsigned short B_lds[BN][LDT];
  __shared__ float g_lds[DDIM];
  __shared__ float partS[BM][8];
  __shared__ float partQ[BM][8];
  __shared__ float mu_lds[BM];
  __shared__ float rs_lds[BM];

  int bid = blockIdx.x;
  int swz = (bid & 7) * ((int)gridDim.x >> 3) + (bid >> 3);
  const int NBN = DDIM / BN; // 6
  int bn = swz % NBN, bm = swz / NBN;
  int m0 = bm * BM, n0 = bn * BN;
  int t = threadIdx.x;
  int lane = t & 63, wave = t >> 6;
  int wm = wave >> 1, wn = wave & 1;
  int lr = lane & 15, lh = lane >> 4;
  int b = m0 / NP;

  for (int i = t; i < DDIM; i += 256) g_lds[i] = g[(size_t)b * DDIM + i];
  __syncthreads();

  f32x4 acc[4][4] = {};
  int c8 = t & 7, rr = t >> 3;
  float sum4[4] = {0.f,0.f,0.f,0.f}, sq4[4] = {0.f,0.f,0.f,0.f};

  for (int ks = 0; ks < DDIM / BK; ++ks){
    int k0 = ks * BK;
    // stage A: k*g -> bf16 LDS; accumulate LN row stats on the fly
    #pragma unroll
    for (int s = 0; s < 4; ++s){
      int row = rr + s * 32;
      u32x4 raw = *reinterpret_cast<const u32x4*>(kin + (size_t)(m0 + row) * DDIM + k0 + c8 * 8);
      u32x4 w;
      #pragma unroll
      for (int i = 0; i < 4; ++i){
        float vlo = b2f_lo(raw[i]);
        float vhi = b2f_hi(raw[i]);
        sum4[s] += vlo + vhi;
        sq4[s] += vlo * vlo + vhi * vhi;
        float g0 = g_lds[k0 + c8 * 8 + 2 * i];
        float g1 = g_lds[k0 + c8 * 8 + 2 * i + 1];
        w[i] = pack2(vlo * g0, vhi * g1);
      }
      *reinterpret_cast<u32x4*>(&A_lds[row][c8 * 8]) = w;
    }
    #pragma unroll
    for (int s = 0; s < 4; ++s){
      int row = rr + s * 32;
      u32x4 w = *reinterpret_cast<const u32x4*>(wt2 + (size_t)(n0 + row) * DDIM + k0 + c8 * 8);
      *reinterpret_cast<u32x4*>(&B_lds[row][c8 * 8]) = w;
    }
    __syncthreads();
    #pragma unroll
    for (int kk = 0; kk < 2; ++kk){
      bf16x8 af[4], bfr[4];
      #pragma unroll
      for (int i = 0; i < 4; ++i)
        af[i] = *reinterpret_cast<const bf16x8*>(&A_lds[wm * 64 + i * 16 + lr][kk * 32 + lh * 8]);
      #pragma unroll
      for (int i = 0; i < 4; ++i)
        bfr[i] = *reinterpret_cast<const bf16x8*>(&B_lds[wn * 64 + i * 16 + lr][kk * 32 + lh * 8]);
      #pragma unroll
      for (int i = 0; i < 4; ++i)
        #pragma unroll
        for (int j = 0; j < 4; ++j)
          acc[i][j] = __builtin_amdgcn_mfma_f32_16x16x32_bf16(af[i], bfr[j], acc[i][j], 0, 0, 0);
    }
    __syncthreads();
  }

  // LN row stats: reduce across the 8 col8 slices
  #pragma unroll
  for (int s = 0; s < 4; ++s){
    partS[rr + s * 32][c8] = sum4[s];
    partQ[rr + s * 32][c8] = sq4[s];
  }
  __syncthreads();
  if (t < BM){
    float s = 0.f, q = 0.f;
    #pragma unroll
    for (int i = 0; i < 8; ++i){ s += partS[t][i]; q += partQ[t][i]; }
    float mu = s * (1.0f / DDIM);
    float var = q * (1.0f / DDIM) - mu * mu;
    mu_lds[t] = mu;
    rs_lds[t] = rsqrtf(var + LNEPS);
  }
  __syncthreads();

  #pragma unroll
  for (int nf = 0; nf < 4; ++nf){
    int colb = wn * 64 + nf * 16 + lr;
    int col = n0 + colb;
    float bpv = bp[col], gmv = gamma[col], btv = beta[col];
    #pragma unroll
    for (int mf = 0; mf < 4; ++mf){
      #pragma unroll
      for (int r = 0; r < 4; ++r){
        int rowb = wm * 64 + mf * 16 + lh * 4 + r;
        size_t gi = (size_t)(m0 + rowb) * DDIM + col;
        float kv = b2f(kin[gi]);
        float ln = (kv - mu_lds[rowb]) * rs_lds[rowb] * gmv + btv;
        out[gi] = acc[mf][nf][r] + bpv + ln;
      }
    }
  }
}

extern "C" void kernel_launch(void* const* d_in, const int* in_sizes, int n_in,
                              void* d_out, int out_size, void* d_ws, size_t ws_size,
                              hipStream_t stream)
{
  const float* x      = (const float*)d_in[0];
  const float* wq     = (const float*)d_in[1];
  const float* bq     = (const float*)d_in[2];
  const float* wk     = (const float*)d_in[3];
  const float* bk     = (const float*)d_in[4];
  const float* w_g    = (const float*)d_in[5];
  const float* w_fc   = (const float*)d_in[6];
  const float* b_fc   = (const float*)d_in[7];
  const float* w_fc2  = (const float*)d_in[8];
  const float* b_fc2  = (const float*)d_in[9];
  const float* w_proj = (const float*)d_in[10];
  const float* b_proj = (const float*)d_in[11];
  const float* gamma  = (const float*)d_in[12];
  const float* beta   = (const float*)d_in[13];
  float* out = (float*)d_out;

  char* ws = (char*)d_ws;
  unsigned short* kbuf = (unsigned short*)(ws);                 // 100,663,296 B
  unsigned short* wt1  = (unsigned short*)(ws + 100663296);     //   2,359,296 B
  unsigned short* wt2  = (unsigned short*)(ws + 103022592);     //   1,179,648 B
  float* qwp = (float*)(ws + 104202240);                        //   1,572,864 B
  float* qsp = (float*)(ws + 105775104);                        //   1,572,864 B
  float* ksp = (float*)(ws + 107347968);                        //   1,572,864 B
  float* g   = (float*)(ws + 108920832);                        //      49,152 B

  prep_w<<<dim3((N1 * DDIM + DDIM * DDIM) / 256), dim3(256), 0, stream>>>(wq, wk, w_proj, wt1, wt2);
  gemm_qk<<<dim3((MTOT / BM) * (N1 / BN)), dim3(256), 0, stream>>>(
      x, wt1, bq, bk, w_g, kbuf, qwp, qsp, ksp);
  combine<<<dim3(NB), dim3(256), 0, stream>>>(qwp, qsp, ksp, w_fc, b_fc, w_fc2, b_fc2, g);
  gemm_out<<<dim3((MTOT / BM) * (DDIM / BN)), dim3(256), 0, stream>>>(
      kbuf, wt2, g, b_proj, gamma, beta, out);
}

// Round 2
// 557.146 us; speedup vs baseline: 1.6988x; 1.6988x over previous
//
#include <hip/hip_runtime.h>
#include <hip/hip_bf16.h>
#include <math.h>

#define NB 16
#define NP 4096
#define DDIM 768
#define MTOT (NB*NP)     // 65536
#define N1 1536
#define BM 128
#define BN 128
#define BK 64
#define SCALEF 0.015625f // 4096^-0.5
#define LNEPS 1e-5f

typedef __attribute__((ext_vector_type(8))) short bf16x8;
typedef __attribute__((ext_vector_type(4))) float f32x4;
typedef __attribute__((ext_vector_type(4))) unsigned int u32x4;
typedef unsigned short us;

__device__ __forceinline__ us f2b(float f){
  union { float f; unsigned int u; } v; v.f = f;
  unsigned int u = v.u;
  unsigned int r = (u + 0x7FFFu + ((u >> 16) & 1u)) >> 16; // RNE
  return (us)r;
}
__device__ __forceinline__ unsigned int pack2(float a, float b){
  return (unsigned int)f2b(a) | ((unsigned int)f2b(b) << 16);
}
__device__ __forceinline__ float b2f(us h){
  union { unsigned int u; float f; } v; v.u = ((unsigned int)h) << 16;
  return v.f;
}
__device__ __forceinline__ float b2f_lo(unsigned int u){
  union { unsigned int x; float f; } v; v.x = u << 16; return v.f;
}
__device__ __forceinline__ float b2f_hi(unsigned int u){
  union { unsigned int x; float f; } v; v.x = u & 0xFFFF0000u; return v.f;
}

typedef __attribute__((address_space(1))) const unsigned int gas_u32;
typedef __attribute__((address_space(3))) unsigned int las_u32;
__device__ __forceinline__ void gl2lds16(const void* g, void* l){
  __builtin_amdgcn_global_load_lds((gas_u32*)g, (las_u32*)l, 16, 0, 0);
}

// ---------------- convert x (f32) -> xb (bf16), 8 elems/thread
__global__ __launch_bounds__(256) void convert_x(const float* __restrict__ x,
                                                 us* __restrict__ xb){
  size_t i = ((size_t)blockIdx.x * 256 + threadIdx.x) * 8;
  const float4* s = reinterpret_cast<const float4*>(x + i);
  float4 a = s[0], b = s[1];
  u32x4 w;
  w[0] = pack2(a.x, a.y); w[1] = pack2(a.z, a.w);
  w[2] = pack2(b.x, b.y); w[3] = pack2(b.z, b.w);
  *reinterpret_cast<u32x4*>(xb + i) = w;
}

// ---------------- prep: Wt1[n][k] = [wq|wk]^T (bf16), Wt2[n][k] = w_proj^T (bf16)
__global__ __launch_bounds__(256) void prep_w(const float* __restrict__ wq,
                                              const float* __restrict__ wk,
                                              const float* __restrict__ wp,
                                              us* __restrict__ wt1,
                                              us* __restrict__ wt2){
  int idx = blockIdx.x * 256 + threadIdx.x;
  const int tot1 = N1 * DDIM;
  if (idx < tot1){
    int n = idx / DDIM, k = idx % DDIM;
    float v = (n < DDIM) ? wq[k * DDIM + n] : wk[k * DDIM + (n - DDIM)];
    wt1[idx] = f2b(v);
  }
  int idx2 = idx - tot1;
  if (idx2 >= 0 && idx2 < DDIM * DDIM){
    int n = idx2 / DDIM, k = idx2 % DDIM;
    wt2[idx2] = f2b(wp[k * DDIM + n]);
  }
}

// ---------------- prep_wb: wbuf[b][n][d] = bf16( g[b][d] * w_proj[d][n] ) via wt2
__global__ __launch_bounds__(256) void prep_wb(const us* __restrict__ wt2,
                                               const float* __restrict__ g,
                                               us* __restrict__ wbuf){
  size_t idx = (size_t)blockIdx.x * 256 + threadIdx.x; // 16*768*768
  int d = (int)(idx % DDIM);
  size_t nd = idx / DDIM;
  int n = (int)(nd % DDIM);
  int b = (int)(nd / DDIM);
  float v = b2f(wt2[n * DDIM + d]) * g[(size_t)b * DDIM + d];
  wbuf[idx] = f2b(v);
}

// ---------------- ln_stats: per-row mean / rsqrt(var+eps) of k (bf16)
__global__ __launch_bounds__(256) void ln_stats(const us* __restrict__ kin,
                                                float2* __restrict__ rstats){
  int row = blockIdx.x * 4 + (threadIdx.x >> 6);
  int l = threadIdx.x & 63;
  const us* rp = kin + (size_t)row * DDIM;
  float s = 0.f, q = 0.f;
  bf16x8 v = *reinterpret_cast<const bf16x8*>(rp + l * 8);
  #pragma unroll
  for (int j = 0; j < 8; ++j){ float f = b2f((us)v[j]); s += f; q += f * f; }
  uint2 w2 = *reinterpret_cast<const uint2*>(rp + 512 + l * 4);
  { float f0 = b2f_lo(w2.x), f1 = b2f_hi(w2.x), f2 = b2f_lo(w2.y), f3 = b2f_hi(w2.y);
    s += f0 + f1 + f2 + f3; q += f0*f0 + f1*f1 + f2*f2 + f3*f3; }
  #pragma unroll
  for (int off = 1; off < 64; off <<= 1){
    s += __shfl_xor(s, off);
    q += __shfl_xor(q, off);
  }
  if (l == 0){
    float mu = s * (1.0f / DDIM);
    float var = q * (1.0f / DDIM) - mu * mu;
    rstats[row] = make_float2(mu, rsqrtf(var + LNEPS));
  }
}

// ---------------- GEMM1: [q|k] = xb @ wt1^T + bias (2-phase gload_lds pipeline)
__global__ __launch_bounds__(256) void gemm_qk(
    const us* __restrict__ xb, const us* __restrict__ wt1,
    const float* __restrict__ bq, const float* __restrict__ bk,
    const float* __restrict__ w_g,
    us* __restrict__ kout,
    float* __restrict__ qwp, float* __restrict__ qsp, float* __restrict__ ksp)
{
  __shared__ us lds[2][2][BM * BK]; // 64 KB exactly; epilogue scratch overlaid

  int bid = blockIdx.x;
  int swz = (bid & 7) * ((int)gridDim.x >> 3) + (bid >> 3);
  const int NBN = N1 / BN; // 12 — n fastest so A-panel is L2-shared
  int bn = swz % NBN, bm = swz / NBN;
  int m0 = bm * BM, n0 = bn * BN;
  int t = threadIdx.x, lane = t & 63, wave = t >> 6;
  int wm = wave >> 1, wn = wave & 1;
  int lr = lane & 15, lh = lane >> 4;

  // per-lane global srcs for the 4 A-chunks + 4 B-chunks this wave stages
  const us* pa[4]; const us* pb[4];
  #pragma unroll
  for (int i = 0; i < 4; ++i){
    int c = wave * 4 + i;
    int u = c * 64 + lane;
    int row = u >> 3, cell = u & 7;
    pa[i] = xb  + (size_t)(m0 + row) * DDIM + cell * 8;
    pb[i] = wt1 + (size_t)(n0 + row) * DDIM + cell * 8;
  }
  auto stage = [&](int bufi, int ks){
    int ko = ks * BK;
    #pragma unroll
    for (int i = 0; i < 4; ++i){
      int c = wave * 4 + i;
      gl2lds16(pa[i] + ko, &lds[bufi][0][c * 512]);
      gl2lds16(pb[i] + ko, &lds[bufi][1][c * 512]);
    }
  };

  f32x4 acc[4][4] = {};
  stage(0, 0);
  __syncthreads();
  int buf = 0;
  for (int ks = 0; ks < DDIM / BK; ++ks){
    if (ks < DDIM / BK - 1) stage(buf ^ 1, ks + 1);
    #pragma unroll
    for (int kk = 0; kk < 2; ++kk){
      bf16x8 af[4], bfr[4];
      #pragma unroll
      for (int i = 0; i < 4; ++i)
        af[i] = *reinterpret_cast<const bf16x8*>(&lds[buf][0][(wm*64 + i*16 + lr)*BK + kk*32 + lh*8]);
      #pragma unroll
      for (int i = 0; i < 4; ++i)
        bfr[i] = *reinterpret_cast<const bf16x8*>(&lds[buf][1][(wn*64 + i*16 + lr)*BK + kk*32 + lh*8]);
      #pragma unroll
      for (int i = 0; i < 4; ++i)
        #pragma unroll
        for (int j = 0; j < 4; ++j)
          acc[i][j] = __builtin_amdgcn_mfma_f32_16x16x32_bf16(af[i], bfr[j], acc[i][j], 0, 0, 0);
    }
    __syncthreads();
    buf ^= 1;
  }

  // ---- epilogue (lds reused: stash @ buf0, partials @ buf1)
  bool is_q = (n0 < DDIM);
  int b = m0 / NP, mc = (m0 % NP) / BM;
  float* part0 = reinterpret_cast<float*>(&lds[1][0][0]);
  float* part1 = part0 + BM * 8;
  us* stash = &lds[0][0][0];

  float wgv[4][4];
  if (is_q){
    #pragma unroll
    for (int mf = 0; mf < 4; ++mf)
      #pragma unroll
      for (int r = 0; r < 4; ++r)
        wgv[mf][r] = w_g[(m0 & (NP - 1)) + wm*64 + mf*16 + lh*4 + r];
  }

  float r0a[4], r1a[4];
  #pragma unroll
  for (int nf = 0; nf < 4; ++nf){
    int colb = wn*64 + nf*16 + lr;
    int col = n0 + colb;
    float bias = is_q ? bq[col] : bk[col - DDIM];
    float s0 = 0.f, s1 = 0.f;
    #pragma unroll
    for (int mf = 0; mf < 4; ++mf){
      #pragma unroll
      for (int r = 0; r < 4; ++r){
        int rowb = wm*64 + mf*16 + lh*4 + r;
        float val = acc[mf][nf][r] + bias;   // C/D: col=lane&15, row=(lane>>4)*4+r
        if (is_q){ s0 += wgv[mf][r] * val; s1 += val; }
        else     { s0 += val; stash[rowb * BN + colb] = f2b(val); }
      }
    }
    r0a[nf] = s0; r1a[nf] = s1;
  }
  int slot = wm * 4 + lh;
  #pragma unroll
  for (int nf = 0; nf < 4; ++nf){
    int colb = wn*64 + nf*16 + lr;
    part0[colb * 8 + slot] = r0a[nf];
    part1[colb * 8 + slot] = r1a[nf];
  }
  __syncthreads();
  if (!is_q){
    #pragma unroll
    for (int s = 0; s < 8; ++s){
      int u = s * 256 + t;
      int row = u >> 4, cu = u & 15;
      *reinterpret_cast<u32x4*>(kout + (size_t)(m0 + row) * DDIM + (n0 - DDIM) + cu * 8) =
          *reinterpret_cast<const u32x4*>(stash + row * BN + cu * 8);
    }
  }
  if (t < BM){
    float s0 = 0.f, s1 = 0.f;
    #pragma unroll
    for (int i = 0; i < 8; ++i){ s0 += part0[t * 8 + i]; s1 += part1[t * 8 + i]; }
    size_t base = ((size_t)b * 32 + mc) * DDIM;
    if (is_q){ qwp[base + n0 + t] = s0; qsp[base + n0 + t] = s1; }
    else       ksp[base + (n0 - DDIM) + t] = s0;
  }
}

// ---------------- combine: per batch — softmax over d, gating chain, g
__global__ __launch_bounds__(256) void combine(
    const float* __restrict__ qwp, const float* __restrict__ qsp, const float* __restrict__ ksp,
    const float* __restrict__ w_fc, const float* __restrict__ b_fc,
    const float* __restrict__ w_fc2, const float* __restrict__ b_fc2,
    float* __restrict__ g)
{
  __shared__ float smA[DDIM];
  __shared__ float smQM[DDIM];
  __shared__ float smKS[DDIM];
  __shared__ float tmat[12][DDIM];
  __shared__ float red[256];
  __shared__ float wbar[12];
  __shared__ float bbar;
  int b = blockIdx.x, t = threadIdx.x;

  for (int col = t; col < DDIM; col += 256){
    float s0 = 0.f, s1 = 0.f, s2 = 0.f;
    for (int mc = 0; mc < 32; ++mc){
      size_t base = ((size_t)b * 32 + mc) * DDIM + col;
      s0 += qwp[base]; s1 += qsp[base]; s2 += ksp[base];
    }
    smA[col] = s0 * SCALEF;
    smQM[col] = s1 * (1.0f / NP);
    smKS[col] = s2;
  }
  __syncthreads();
  float lmax = -1e30f;
  for (int col = t; col < DDIM; col += 256) lmax = fmaxf(lmax, smA[col]);
  red[t] = lmax; __syncthreads();
  for (int off = 128; off; off >>= 1){
    if (t < off) red[t] = fmaxf(red[t], red[t + off]);
    __syncthreads();
  }
  float mx = red[0];
  __syncthreads();
  float lsum = 0.f;
  for (int col = t; col < DDIM; col += 256){
    float e = __expf(smA[col] - mx);
    smA[col] = e; lsum += e;
  }
  red[t] = lsum; __syncthreads();
  for (int off = 128; off; off >>= 1){
    if (t < off) red[t] += red[t + off];
    __syncthreads();
  }
  float inv = 1.0f / red[0];
  for (int col = t; col < DDIM; col += 256) smA[col] *= inv;

  if (t < 12){
    float s = 0.f;
    for (int j = 0; j < 12; ++j) s += w_fc2[t * 12 + j];
    wbar[t] = s * (1.0f / 12.0f);
  }
  if (t == 12){
    float s = 0.f;
    for (int j = 0; j < 12; ++j) s += b_fc2[j];
    bbar = s * (1.0f / 12.0f);
  }
  __syncthreads();
  for (int idx = t; idx < 12 * DDIM; idx += 256){
    int h = idx / DDIM, j = idx % DDIM;
    float s = b_fc[j];
    const float* qm = &smQM[h * 64];
    #pragma unroll 4
    for (int i = 0; i < 64; ++i) s += qm[i] * w_fc[i * DDIM + j];
    tmat[h][j] = 0.5f * s * (1.0f + erff(s * 0.70710678118654752f));
  }
  __syncthreads();
  for (int p = t; p < DDIM; p += 256){
    float s = bbar;
    #pragma unroll
    for (int m = 0; m < 12; ++m){
      int f = p * 12 + m;                 // torch reshape (b,12,768)->(b,768,12)
      s += tmat[f / DDIM][f % DDIM] * wbar[m];
    }
    float dv = 1.0f / (1.0f + __expf(-s));
    g[(size_t)b * DDIM + p] = smA[p] * smKS[p] * dv;
  }
}

// ---------------- GEMM2: out = k @ (g-scaled w_proj) + b_proj + layernorm(k)
__global__ __launch_bounds__(256) void gemm_out(
    const us* __restrict__ kin, const us* __restrict__ wbuf,
    const float2* __restrict__ rstats,
    const float* __restrict__ bp, const float* __restrict__ gamma,
    const float* __restrict__ beta,
    float* __restrict__ out)
{
  __shared__ us lds[2][2][BM * BK]; // 64 KB

  int bid = blockIdx.x;
  int swz = (bid & 7) * ((int)gridDim.x >> 3) + (bid >> 3);
  const int NBN = DDIM / BN; // 6
  int bn = swz % NBN, bm = swz / NBN;
  int m0 = bm * BM, n0 = bn * BN;
  int t = threadIdx.x, lane = t & 63, wave = t >> 6;
  int wm = wave >> 1, wn = wave & 1;
  int lr = lane & 15, lh = lane >> 4;
  int b = m0 / NP;
  const us* wb = wbuf + (size_t)b * DDIM * DDIM;

  const us* pa[4]; const us* pb[4];
  #pragma unroll
  for (int i = 0; i < 4; ++i){
    int c = wave * 4 + i;
    int u = c * 64 + lane;
    int row = u >> 3, cell = u & 7;
    pa[i] = kin + (size_t)(m0 + row) * DDIM + cell * 8;
    pb[i] = wb  + (size_t)(n0 + row) * DDIM + cell * 8;
  }
  auto stage = [&](int bufi, int ks){
    int ko = ks * BK;
    #pragma unroll
    for (int i = 0; i < 4; ++i){
      int c = wave * 4 + i;
      gl2lds16(pa[i] + ko, &lds[bufi][0][c * 512]);
      gl2lds16(pb[i] + ko, &lds[bufi][1][c * 512]);
    }
  };

  f32x4 acc[4][4] = {};
  stage(0, 0);
  __syncthreads();
  int buf = 0;
  for (int ks = 0; ks < DDIM / BK; ++ks){
    if (ks < DDIM / BK - 1) stage(buf ^ 1, ks + 1);
    #pragma unroll
    for (int kk = 0; kk < 2; ++kk){
      bf16x8 af[4], bfr[4];
      #pragma unroll
      for (int i = 0; i < 4; ++i)
        af[i] = *reinterpret_cast<const bf16x8*>(&lds[buf][0][(wm*64 + i*16 + lr)*BK + kk*32 + lh*8]);
      #pragma unroll
      for (int i = 0; i < 4; ++i)
        bfr[i] = *reinterpret_cast<const bf16x8*>(&lds[buf][1][(wn*64 + i*16 + lr)*BK + kk*32 + lh*8]);
      #pragma unroll
      for (int i = 0; i < 4; ++i)
        #pragma unroll
        for (int j = 0; j < 4; ++j)
          acc[i][j] = __builtin_amdgcn_mfma_f32_16x16x32_bf16(af[i], bfr[j], acc[i][j], 0, 0, 0);
    }
    __syncthreads();
    buf ^= 1;
  }

  // ---- epilogue: stage kin block (coalesced), finalize, relayout, float4 out
  us* stash = &lds[0][0][0];           // 32 KB: 128x128 bf16
  #pragma unroll
  for (int s = 0; s < 8; ++s){
    int u = s * 256 + t;
    int row = u >> 4, cu = u & 15;
    *reinterpret_cast<u32x4*>(stash + row * BN + cu * 8) =
        *reinterpret_cast<const u32x4*>(kin + (size_t)(m0 + row) * DDIM + n0 + cu * 8);
  }
  float muv[4][4], rsv[4][4];
  #pragma unroll
  for (int mf = 0; mf < 4; ++mf)
    #pragma unroll
    for (int r = 0; r < 4; ++r){
      float2 st = rstats[m0 + wm*64 + mf*16 + lh*4 + r];
      muv[mf][r] = st.x; rsv[mf][r] = st.y;
    }
  __syncthreads();
  #pragma unroll
  for (int nf = 0; nf < 4; ++nf){
    int colb = wn*64 + nf*16 + lr;
    int col = n0 + colb;
    float bpv = bp[col], gmv = gamma[col], btv = beta[col];
    #pragma unroll
    for (int mf = 0; mf < 4; ++mf){
      #pragma unroll
      for (int r = 0; r < 4; ++r){
        int rowb = wm*64 + mf*16 + lh*4 + r;
        float kv = b2f(stash[rowb * BN + colb]);
        acc[mf][nf][r] = acc[mf][nf][r] + bpv + (kv - muv[mf][r]) * rsv[mf][r] * gmv + btv;
      }
    }
  }
  __syncthreads();
  float* ldsf = reinterpret_cast<float*>(&lds[0][0][0]); // 64 KB: 128x128 f32
  #pragma unroll
  for (int nf = 0; nf < 4; ++nf){
    int colb = wn*64 + nf*16 + lr;
    #pragma unroll
    for (int mf = 0; mf < 4; ++mf)
      #pragma unroll
      for (int r = 0; r < 4; ++r)
        ldsf[(wm*64 + mf*16 + lh*4 + r) * BN + colb] = acc[mf][nf][r];
  }
  __syncthreads();
  #pragma unroll
  for (int s = 0; s < 16; ++s){
    int u = s * 256 + t;
    int row = u >> 5, cu = u & 31;
    *reinterpret_cast<float4*>(out + (size_t)(m0 + row) * DDIM + n0 + cu * 4) =
        *reinterpret_cast<const float4*>(ldsf + row * BN + cu * 4);
  }
}

extern "C" void kernel_launch(void* const* d_in, const int* in_sizes, int n_in,
                              void* d_out, int out_size, void* d_ws, size_t ws_size,
                              hipStream_t stream)
{
  const float* x      = (const float*)d_in[0];
  const float* wq     = (const float*)d_in[1];
  const float* bq     = (const float*)d_in[2];
  const float* wk     = (const float*)d_in[3];
  const float* bk     = (const float*)d_in[4];
  const float* w_g    = (const float*)d_in[5];
  const float* w_fc   = (const float*)d_in[6];
  const float* b_fc   = (const float*)d_in[7];
  const float* w_fc2  = (const float*)d_in[8];
  const float* b_fc2  = (const float*)d_in[9];
  const float* w_proj = (const float*)d_in[10];
  const float* b_proj = (const float*)d_in[11];
  const float* gamma  = (const float*)d_in[12];
  const float* beta   = (const float*)d_in[13];
  float* out = (float*)d_out;

  char* ws = (char*)d_ws;
  us*     xb    = (us*)(ws);                       // 100,663,296 B
  us*     kbuf  = (us*)(ws + 100663296);           // 100,663,296 B
  us*     wt1   = (us*)(ws + 201326592);           //   2,359,296 B
  us*     wt2   = (us*)(ws + 203685888);           //   1,179,648 B
  us*     wbuf  = (us*)(ws + 204865536);           //  18,874,368 B
  float*  qwp   = (float*)(ws + 223739904);        //   1,572,864 B
  float*  qsp   = (float*)(ws + 225312768);        //   1,572,864 B
  float*  ksp   = (float*)(ws + 226885632);        //   1,572,864 B
  float*  g     = (float*)(ws + 228458496);        //      49,152 B
  float2* rstat = (float2*)(ws + 228507648);       //     524,288 B  (total ~218.4 MiB)

  convert_x<<<dim3(MTOT * DDIM / (256 * 8)), dim3(256), 0, stream>>>(x, xb);
  prep_w<<<dim3((N1 * DDIM + DDIM * DDIM) / 256), dim3(256), 0, stream>>>(wq, wk, w_proj, wt1, wt2);
  gemm_qk<<<dim3((MTOT / BM) * (N1 / BN)), dim3(256), 0, stream>>>(
      xb, wt1, bq, bk, w_g, kbuf, qwp, qsp, ksp);
  ln_stats<<<dim3(MTOT / 4), dim3(256), 0, stream>>>(kbuf, rstat);
  combine<<<dim3(NB), dim3(256), 0, stream>>>(qwp, qsp, ksp, w_fc, b_fc, w_fc2, b_fc2, g);
  prep_wb<<<dim3(NB * DDIM * DDIM / 256), dim3(256), 0, stream>>>(wt2, g, wbuf);
  gemm_out<<<dim3((MTOT / BM) * (DDIM / BN)), dim3(256), 0, stream>>>(
      kbuf, wbuf, rstat, b_proj, gamma, beta, out);
}

// Round 4
// 535.404 us; speedup vs baseline: 1.7677x; 1.0406x over previous
//
#include <hip/hip_runtime.h>
#include <hip/hip_bf16.h>
#include <math.h>

#define NB 16
#define NP 4096
#define DDIM 768
#define MTOT (NB*NP)     // 65536
#define N1 1536
#define SCALEF 0.015625f // 4096^-0.5
#define LNEPS 1e-5f

typedef __attribute__((ext_vector_type(8))) short bf16x8;
typedef __attribute__((ext_vector_type(4))) float f32x4;
typedef __attribute__((ext_vector_type(4))) unsigned int u32x4;
typedef unsigned short us;

__device__ __forceinline__ us f2b(float f){
  union { float f; unsigned int u; } v; v.f = f;
  unsigned int u = v.u;
  unsigned int r = (u + 0x7FFFu + ((u >> 16) & 1u)) >> 16; // RNE
  return (us)r;
}
__device__ __forceinline__ unsigned int pack2(float a, float b){
  return (unsigned int)f2b(a) | ((unsigned int)f2b(b) << 16);
}
__device__ __forceinline__ float b2f(us h){
  union { unsigned int u; float f; } v; v.u = ((unsigned int)h) << 16;
  return v.f;
}
__device__ __forceinline__ float b2f_lo(unsigned int u){
  union { unsigned int x; float f; } v; v.x = u << 16; return v.f;
}
__device__ __forceinline__ float b2f_hi(unsigned int u){
  union { unsigned int x; float f; } v; v.x = u & 0xFFFF0000u; return v.f;
}

typedef __attribute__((address_space(1))) const unsigned int gas_u32;
typedef __attribute__((address_space(3))) unsigned int las_u32;
__device__ __forceinline__ void gl2lds16(const void* g, void* l){
  __builtin_amdgcn_global_load_lds((gas_u32*)g, (las_u32*)l, 16, 0, 0);
}

// ---------------- convert x (f32) -> xb (bf16)
__global__ __launch_bounds__(256) void convert_x(const float* __restrict__ x,
                                                 us* __restrict__ xb){
  size_t i = ((size_t)blockIdx.x * 256 + threadIdx.x) * 8;
  const float4* s = reinterpret_cast<const float4*>(x + i);
  float4 a = s[0], b = s[1];
  u32x4 w;
  w[0] = pack2(a.x, a.y); w[1] = pack2(a.z, a.w);
  w[2] = pack2(b.x, b.y); w[3] = pack2(b.z, b.w);
  *reinterpret_cast<u32x4*>(xb + i) = w;
}

// ---------------- prep: Wt1[n][k] = [wq|wk]^T (bf16), Wt2[n][k] = w_proj^T (bf16)
__global__ __launch_bounds__(256) void prep_w(const float* __restrict__ wq,
                                              const float* __restrict__ wk,
                                              const float* __restrict__ wp,
                                              us* __restrict__ wt1,
                                              us* __restrict__ wt2){
  int idx = blockIdx.x * 256 + threadIdx.x;
  const int tot1 = N1 * DDIM;
  if (idx < tot1){
    int n = idx / DDIM, k = idx % DDIM;
    float v = (n < DDIM) ? wq[k * DDIM + n] : wk[k * DDIM + (n - DDIM)];
    wt1[idx] = f2b(v);
  }
  int idx2 = idx - tot1;
  if (idx2 >= 0 && idx2 < DDIM * DDIM){
    int n = idx2 / DDIM, k = idx2 % DDIM;
    wt2[idx2] = f2b(wp[k * DDIM + n]);
  }
}

// ---------------- prep_wb: wbuf[b][n][d] = bf16( g[b][d] * w_proj[d][n] )
__global__ __launch_bounds__(256) void prep_wb(const us* __restrict__ wt2,
                                               const float* __restrict__ g,
                                               us* __restrict__ wbuf){
  size_t idx = (size_t)blockIdx.x * 256 + threadIdx.x;
  int d = (int)(idx % DDIM);
  size_t nd = idx / DDIM;
  int n = (int)(nd % DDIM);
  int b = (int)(nd / DDIM);
  float v = b2f(wt2[n * DDIM + d]) * g[(size_t)b * DDIM + d];
  wbuf[idx] = f2b(v);
}

// ---------------- ln_reduce: rstats from 3 col-block partials per row
__global__ __launch_bounds__(256) void ln_reduce(const float* __restrict__ lnS,
                                                 const float* __restrict__ lnQ,
                                                 float2* __restrict__ rstats){
  int r = blockIdx.x * 256 + threadIdx.x;
  float s = lnS[r] + lnS[MTOT + r] + lnS[2*MTOT + r];
  float q = lnQ[r] + lnQ[MTOT + r] + lnQ[2*MTOT + r];
  float mu = s * (1.0f / DDIM);
  float var = q * (1.0f / DDIM) - mu * mu;
  rstats[r] = make_float2(mu, rsqrtf(var + LNEPS));
}

// ================ 256x256 8-wave quadrant-phased pipelined GEMM core =========
// LDS (128 KB as us[65536]): A = 4 half-tile slots of [128][64] bf16 (16 KB each),
// B same at +32768 us. Ring slot for half h of K-tile kt: (2kt+h)&3.
// Phase p computes C-quadrant (qm=p>>1, qn=p&1): reads A-half qm, B-half qn only.
// Staging: kt in [1,10] stages kt+1's halves, one per phase (order A0,B0,B1,A1);
// kt0+kt1 staged in prologue. vmcnt(4) per phase (8 prologue; drain 2,0 at kt=11).
// Bank swizzle: LDS[row][cell] = global[row][cell ^ (row&7)] (cell = 16B unit,
// 8 per row). gload_lds writes linearly, so the XOR is applied on the global
// SOURCE address; the ds_read de-swizzles with cell = ((kk<<2)|lh) ^ (lane&7)
// (FULL 3-bit cell XOR — R3 bug was XORing only lh, overflowing the row).
__device__ __forceinline__ void gemm256_core(const us* __restrict__ Ag,
                                             const us* __restrict__ Bg,
                                             us* lds, int t,
                                             f32x4 (&acc)[4][4][2]){
  us* ldsA = lds;
  us* ldsB = lds + 32768;
  const int wave = t >> 6, lane = t & 63;
  const int wr = wave >> 2, wc = wave & 3, lr = lane & 15, lh = lane >> 4;
  const int srow = t >> 3;                  // 0..63
  const int scell = (t & 7) ^ ((t >> 3) & 7);
  const int key8 = lane & 7;                // == row&7 for all fragment rows

  auto stage = [&](int sel, int h, int kt){
    const us* gb = sel ? Bg : Ag;
    us* lb = sel ? ldsB : ldsA;
    int slot = (2*kt + h) & 3;
    #pragma unroll
    for (int j = 0; j < 2; ++j){
      const us* src = gb + (size_t)(h*128 + j*64 + srow) * DDIM + kt*64 + scell*8;
      gl2lds16(src, lb + slot*8192 + j*4096 + (wave << 9));
    }
  };

  // prologue: kt0 fully, kt1 fully (16 loads); kt0 guaranteed by vmcnt(8)
  stage(0,0,0); stage(1,0,0); stage(1,1,0); stage(0,1,0);
  stage(0,0,1); stage(1,0,1); stage(1,1,1); stage(0,1,1);
  asm volatile("s_waitcnt vmcnt(8)" ::: "memory");
  __builtin_amdgcn_s_barrier();

  for (int kt = 0; kt < 12; ++kt){
    #pragma unroll
    for (int p = 0; p < 4; ++p){
      const int qm = p >> 1, qn = p & 1;
      const us* Ab = ldsA + ((2*kt + qm) & 3) * 8192;
      const us* Bb = ldsB + ((2*kt + qn) & 3) * 8192;
      bf16x8 av[4][2], bv[2][2];
      #pragma unroll
      for (int fm = 0; fm < 4; ++fm){
        int ra = wr*64 + fm*16 + lr;
        #pragma unroll
        for (int kk = 0; kk < 2; ++kk)
          av[fm][kk] = *reinterpret_cast<const bf16x8*>(
              &Ab[ra*64 + ((((kk<<2)|lh) ^ key8) << 3)]);
      }
      #pragma unroll
      for (int fn = 0; fn < 2; ++fn){
        int rb = wc*32 + fn*16 + lr;
        #pragma unroll
        for (int kk = 0; kk < 2; ++kk)
          bv[fn][kk] = *reinterpret_cast<const bf16x8*>(
              &Bb[rb*64 + ((((kk<<2)|lh) ^ key8) << 3)]);
      }
      if (kt >= 1 && kt <= 10){
        if      (p == 0) stage(0, 0, kt+1);
        else if (p == 1) stage(1, 0, kt+1);
        else if (p == 2) stage(1, 1, kt+1);
        else             stage(0, 1, kt+1);
      }
      __builtin_amdgcn_sched_barrier(0);
      __builtin_amdgcn_s_barrier();
      __builtin_amdgcn_s_setprio(1);
      #pragma unroll
      for (int fm = 0; fm < 4; ++fm)
        #pragma unroll
        for (int fn = 0; fn < 2; ++fn)
          #pragma unroll
          for (int kk = 0; kk < 2; ++kk)
            acc[p][fm][fn] = __builtin_amdgcn_mfma_f32_16x16x32_bf16(
                av[fm][kk], bv[fn][kk], acc[p][fm][fn], 0, 0, 0);
      __builtin_amdgcn_s_setprio(0);
      if (kt < 11)      { asm volatile("s_waitcnt vmcnt(4)" ::: "memory"); }
      else if (p == 0)  { asm volatile("s_waitcnt vmcnt(2)" ::: "memory"); }
      else if (p == 1)  { asm volatile("s_waitcnt vmcnt(0)" ::: "memory"); }
      __builtin_amdgcn_sched_barrier(0);
      __builtin_amdgcn_s_barrier();
    }
  }
}

// ---------------- GEMM1: [q|k] = xb @ wt1^T + bias
__global__ __launch_bounds__(512, 2) void gemm_qk(
    const us* __restrict__ xb, const us* __restrict__ wt1,
    const float* __restrict__ bq, const float* __restrict__ bk,
    const float* __restrict__ w_g,
    us* __restrict__ kout,
    float* __restrict__ qwp, float* __restrict__ qsp, float* __restrict__ ksp,
    float* __restrict__ lnS, float* __restrict__ lnQ)
{
  extern __shared__ us lds[];
  int bid = blockIdx.x;
  int swz = (bid & 7) * ((int)gridDim.x >> 3) + (bid >> 3);
  int bn = swz % 6, bm = swz / 6;       // n fastest: A-panel shared per XCD chunk
  int m0 = bm * 256, n0 = bn * 256;
  int t = threadIdx.x;

  f32x4 acc[4][4][2] = {};
  gemm256_core(xb + (size_t)m0 * DDIM, wt1 + (size_t)n0 * DDIM, lds, t, acc);

  int wave = t >> 6, lane = t & 63;
  int wr = wave >> 2, wc = wave & 3, lr = lane & 15, lh = lane >> 4;
  bool is_q = (n0 < DDIM);
  int b = m0 >> 12, mc = (m0 & (NP-1)) >> 8;

  float bias[2][2];
  #pragma unroll
  for (int qn = 0; qn < 2; ++qn)
    #pragma unroll
    for (int fn = 0; fn < 2; ++fn){
      int col = qn*128 + wc*32 + fn*16 + lr;
      bias[qn][fn] = is_q ? bq[n0 + col] : bk[n0 - DDIM + col];
    }

  // write 256x256 bf16 tile to LDS (bank-swizzled)
  #pragma unroll
  for (int p = 0; p < 4; ++p){
    int qm = p >> 1, qn = p & 1;
    #pragma unroll
    for (int fm = 0; fm < 4; ++fm)
      #pragma unroll
      for (int r = 0; r < 4; ++r){
        int row = qm*128 + wr*64 + fm*16 + lh*4 + r;
        #pragma unroll
        for (int fn = 0; fn < 2; ++fn){
          int col = qn*128 + wc*32 + fn*16 + lr;
          lds[row*256 + (col ^ ((row & 7) << 3))] = f2b(acc[p][fm][fn][r] + bias[qn][fn]);
        }
      }
  }
  __syncthreads();

  // sweep: coalesced k-store + column partials (+row LN partials for k-blocks)
  int c8 = t & 31, rb = t >> 5;
  float cp[8] = {0,0,0,0,0,0,0,0};
  float cpw[8] = {0,0,0,0,0,0,0,0};
  float rs16[16], rq16[16];
  #pragma unroll
  for (int s = 0; s < 16; ++s){
    int row = s*16 + rb;
    u32x4 ch = *reinterpret_cast<const u32x4*>(&lds[row*256 + ((c8 ^ (row & 7)) << 3)]);
    float v[8];
    #pragma unroll
    for (int i = 0; i < 4; ++i){ v[2*i] = b2f_lo(ch[i]); v[2*i+1] = b2f_hi(ch[i]); }
    if (is_q){
      float wg = w_g[(m0 & (NP-1)) + row];
      #pragma unroll
      for (int j = 0; j < 8; ++j){ cp[j] += v[j]; cpw[j] += wg * v[j]; }
    } else {
      *reinterpret_cast<u32x4*>(kout + (size_t)(m0+row)*DDIM + (n0 - DDIM) + c8*8) = ch;
      float ss = 0.f, qq = 0.f;
      #pragma unroll
      for (int j = 0; j < 8; ++j){ cp[j] += v[j]; ss += v[j]; qq += v[j]*v[j]; }
      rs16[s] = ss; rq16[s] = qq;
    }
  }
  __syncthreads();
  float* colP  = reinterpret_cast<float*>(lds);   // [256][16]
  float* colPw = colP + 4096;                     // [256][16] (q)
  float* rowP  = colP + 8192;                     // [256][32] (k)
  float* rowQ  = colP + 16384;                    // [256][32] (k)
  #pragma unroll
  for (int j = 0; j < 8; ++j){
    colP[(c8*8+j)*16 + rb] = cp[j];
    if (is_q) colPw[(c8*8+j)*16 + rb] = cpw[j];
  }
  if (!is_q){
    #pragma unroll
    for (int s = 0; s < 16; ++s){
      int row = s*16 + rb;
      rowP[row*32 + c8] = rs16[s];
      rowQ[row*32 + c8] = rq16[s];
    }
  }
  __syncthreads();
  if (t < 256){
    float s0 = 0.f;
    #pragma unroll
    for (int i = 0; i < 16; ++i) s0 += colP[t*16 + i];
    size_t base = ((size_t)b * 16 + mc) * DDIM;
    if (is_q){
      float s1 = 0.f;
      #pragma unroll
      for (int i = 0; i < 16; ++i) s1 += colPw[t*16 + i];
      qwp[base + n0 + t] = s1;
      qsp[base + n0 + t] = s0;
    } else {
      ksp[base + (n0 - DDIM) + t] = s0;
      float rs_ = 0.f, rq_ = 0.f;
      #pragma unroll
      for (int i = 0; i < 32; ++i){ rs_ += rowP[t*32 + i]; rq_ += rowQ[t*32 + i]; }
      int kb = bn - 3;
      lnS[(size_t)kb * MTOT + m0 + t] = rs_;
      lnQ[(size_t)kb * MTOT + m0 + t] = rq_;
    }
  }
}

// ---------------- combine: per batch — softmax over d, gating chain, g
__global__ __launch_bounds__(256) void combine(
    const float* __restrict__ qwp, const float* __restrict__ qsp, const float* __restrict__ ksp,
    const float* __restrict__ w_fc, const float* __restrict__ b_fc,
    const float* __restrict__ w_fc2, const float* __restrict__ b_fc2,
    float* __restrict__ g)
{
  __shared__ float smA[DDIM];
  __shared__ float smQM[DDIM];
  __shared__ float smKS[DDIM];
  __shared__ float tmat[12][DDIM];
  __shared__ float red[256];
  __shared__ float wbar[12];
  __shared__ float bbar;
  int b = blockIdx.x, t = threadIdx.x;

  for (int col = t; col < DDIM; col += 256){
    float s0 = 0.f, s1 = 0.f, s2 = 0.f;
    for (int mc = 0; mc < 16; ++mc){
      size_t base = ((size_t)b * 16 + mc) * DDIM + col;
      s0 += qwp[base]; s1 += qsp[base]; s2 += ksp[base];
    }
    smA[col] = s0 * SCALEF;
    smQM[col] = s1 * (1.0f / NP);
    smKS[col] = s2;
  }
  __syncthreads();
  float lmax = -1e30f;
  for (int col = t; col < DDIM; col += 256) lmax = fmaxf(lmax, smA[col]);
  red[t] = lmax; __syncthreads();
  for (int off = 128; off; off >>= 1){
    if (t < off) red[t] = fmaxf(red[t], red[t + off]);
    __syncthreads();
  }
  float mx = red[0];
  __syncthreads();
  float lsum = 0.f;
  for (int col = t; col < DDIM; col += 256){
    float e = __expf(smA[col] - mx);
    smA[col] = e; lsum += e;
  }
  red[t] = lsum; __syncthreads();
  for (int off = 128; off; off >>= 1){
    if (t < off) red[t] += red[t + off];
    __syncthreads();
  }
  float inv = 1.0f / red[0];
  for (int col = t; col < DDIM; col += 256) smA[col] *= inv;

  if (t < 12){
    float s = 0.f;
    for (int j = 0; j < 12; ++j) s += w_fc2[t * 12 + j];
    wbar[t] = s * (1.0f / 12.0f);
  }
  if (t == 12){
    float s = 0.f;
    for (int j = 0; j < 12; ++j) s += b_fc2[j];
    bbar = s * (1.0f / 12.0f);
  }
  __syncthreads();
  for (int idx = t; idx < 12 * DDIM; idx += 256){
    int h = idx / DDIM, j = idx % DDIM;
    float s = b_fc[j];
    const float* qm = &smQM[h * 64];
    #pragma unroll 4
    for (int i = 0; i < 64; ++i) s += qm[i] * w_fc[i * DDIM + j];
    tmat[h][j] = 0.5f * s * (1.0f + erff(s * 0.70710678118654752f));
  }
  __syncthreads();
  for (int p = t; p < DDIM; p += 256){
    float s = bbar;
    #pragma unroll
    for (int m = 0; m < 12; ++m){
      int f = p * 12 + m;                 // torch reshape (b,12,768)->(b,768,12)
      s += tmat[f / DDIM][f % DDIM] * wbar[m];
    }
    float dv = 1.0f / (1.0f + __expf(-s));
    g[(size_t)b * DDIM + p] = smA[p] * smKS[p] * dv;
  }
}

// ---------------- GEMM2: out = k @ (g-scaled w_proj) + b_proj + layernorm(k)
__global__ __launch_bounds__(512, 2) void gemm_out(
    const us* __restrict__ kin, const us* __restrict__ wbuf,
    const float2* __restrict__ rstats,
    const float* __restrict__ bp, const float* __restrict__ gamma,
    const float* __restrict__ beta,
    float* __restrict__ out)
{
  extern __shared__ us lds[];
  int bid = blockIdx.x;
  int swz = (bid & 7) * ((int)gridDim.x >> 3) + (bid >> 3);
  int bn = swz % 3, bm = swz / 3;
  int m0 = bm * 256, n0 = bn * 256;
  int t = threadIdx.x;
  int b = m0 >> 12;

  f32x4 acc[4][4][2] = {};
  gemm256_core(kin + (size_t)m0 * DDIM,
               wbuf + (size_t)b * DDIM * DDIM + (size_t)n0 * DDIM, lds, t, acc);

  int wave = t >> 6, lane = t & 63;
  int wr = wave >> 2, wc = wave & 3, lr = lane & 15, lh = lane >> 4;

  // stage kin 256x256 tile (swizzled source cells, linear LDS dest)
  #pragma unroll
  for (int j = 0; j < 16; ++j){
    int row = j*16 + (t >> 5);
    const us* src = kin + (size_t)(m0 + row) * DDIM + n0 + (((t & 31) ^ (row & 7)) << 3);
    gl2lds16(src, lds + j*4096 + (wave << 9));
  }
  asm volatile("s_waitcnt vmcnt(0)" ::: "memory");
  __syncthreads();

  // fold bias + layernorm(k) into acc
  #pragma unroll
  for (int p = 0; p < 4; ++p){
    int qm = p >> 1, qn = p & 1;
    #pragma unroll
    for (int fn = 0; fn < 2; ++fn){
      int col = qn*128 + wc*32 + fn*16 + lr;
      float bpv = bp[n0 + col], gmv = gamma[n0 + col], btv = beta[n0 + col];
      #pragma unroll
      for (int fm = 0; fm < 4; ++fm)
        #pragma unroll
        for (int r = 0; r < 4; ++r){
          int row = qm*128 + wr*64 + fm*16 + lh*4 + r;
          float2 st = rstats[m0 + row];
          float kv = b2f(lds[row*256 + (col ^ ((row & 7) << 3))]);
          acc[p][fm][fn][r] += bpv + (kv - st.x) * st.y * gmv + btv;
        }
    }
  }
  __syncthreads();

  // two half-passes: relayout f32 through LDS, float4 stores
  float* fb = reinterpret_cast<float*>(lds);   // [256][128] f32 = 128 KB
  #pragma unroll
  for (int h = 0; h < 2; ++h){
    #pragma unroll
    for (int qm2 = 0; qm2 < 2; ++qm2){
      int p = qm2*2 + h;   // phases with qn == h
      #pragma unroll
      for (int fm = 0; fm < 4; ++fm)
        #pragma unroll
        for (int r = 0; r < 4; ++r){
          int row = qm2*128 + wr*64 + fm*16 + lh*4 + r;
          #pragma unroll
          for (int fn = 0; fn < 2; ++fn){
            int c = wc*32 + fn*16 + lr;
            fb[row*128 + (c ^ ((row & 7) << 2))] = acc[p][fm][fn][r];
          }
        }
    }
    __syncthreads();
    #pragma unroll
    for (int s = 0; s < 16; ++s){
      int u = s*512 + t;
      int row = u >> 5, c4 = u & 31;
      float4 vv = *reinterpret_cast<const float4*>(&fb[row*128 + ((c4 ^ (row & 7)) << 2)]);
      *reinterpret_cast<float4*>(&out[(size_t)(m0 + row) * DDIM + n0 + h*128 + c4*4]) = vv;
    }
    __syncthreads();
  }
}

extern "C" void kernel_launch(void* const* d_in, const int* in_sizes, int n_in,
                              void* d_out, int out_size, void* d_ws, size_t ws_size,
                              hipStream_t stream)
{
  const float* x      = (const float*)d_in[0];
  const float* wq     = (const float*)d_in[1];
  const float* bq     = (const float*)d_in[2];
  const float* wk     = (const float*)d_in[3];
  const float* bk     = (const float*)d_in[4];
  const float* w_g    = (const float*)d_in[5];
  const float* w_fc   = (const float*)d_in[6];
  const float* b_fc   = (const float*)d_in[7];
  const float* w_fc2  = (const float*)d_in[8];
  const float* b_fc2  = (const float*)d_in[9];
  const float* w_proj = (const float*)d_in[10];
  const float* b_proj = (const float*)d_in[11];
  const float* gamma  = (const float*)d_in[12];
  const float* beta   = (const float*)d_in[13];
  float* out = (float*)d_out;

  char* ws = (char*)d_ws;
  us*     xb    = (us*)(ws);                       // 100,663,296 B
  us*     kbuf  = (us*)(ws + 100663296);           // 100,663,296 B
  us*     wt1   = (us*)(ws + 201326592);           //   2,359,296 B
  us*     wt2   = (us*)(ws + 203685888);           //   1,179,648 B
  us*     wbuf  = (us*)(ws + 204865536);           //  18,874,368 B
  float*  qwp   = (float*)(ws + 223739904);        //     786,432 B
  float*  qsp   = (float*)(ws + 224526336);        //     786,432 B
  float*  ksp   = (float*)(ws + 225312768);        //     786,432 B
  float*  lnS   = (float*)(ws + 226099200);        //     786,432 B
  float*  lnQ   = (float*)(ws + 226885632);        //     786,432 B
  float*  g     = (float*)(ws + 227672064);        //      49,152 B
  float2* rstat = (float2*)(ws + 227721216);       //     524,288 B  (~217.7 MiB total)

  convert_x<<<dim3(MTOT * DDIM / (256 * 8)), dim3(256), 0, stream>>>(x, xb);
  prep_w<<<dim3((N1 * DDIM + DDIM * DDIM) / 256), dim3(256), 0, stream>>>(wq, wk, w_proj, wt1, wt2);
  gemm_qk<<<dim3((MTOT / 256) * (N1 / 256)), dim3(512), 131072, stream>>>(
      xb, wt1, bq, bk, w_g, kbuf, qwp, qsp, ksp, lnS, lnQ);
  ln_reduce<<<dim3(MTOT / 256), dim3(256), 0, stream>>>(lnS, lnQ, rstat);
  combine<<<dim3(NB), dim3(256), 0, stream>>>(qwp, qsp, ksp, w_fc, b_fc, w_fc2, b_fc2, g);
  prep_wb<<<dim3(NB * DDIM * DDIM / 256), dim3(256), 0, stream>>>(wt2, g, wbuf);
  gemm_out<<<dim3((MTOT / 256) * (DDIM / 256)), dim3(512), 131072, stream>>>(
      kbuf, wbuf, rstat, b_proj, gamma, beta, out);
}

// Round 5
// 520.003 us; speedup vs baseline: 1.8201x; 1.0296x over previous
//
#include <hip/hip_runtime.h>
#include <hip/hip_bf16.h>
#include <math.h>

#define NB 16
#define NP 4096
#define DDIM 768
#define MTOT (NB*NP)     // 65536
#define N1 1536
#define SCALEF 0.015625f // 4096^-0.5
#define LNEPS 1e-5f

typedef __attribute__((ext_vector_type(8))) short bf16x8;
typedef __attribute__((ext_vector_type(4))) float f32x4;
typedef __attribute__((ext_vector_type(4))) unsigned int u32x4;
typedef unsigned short us;

__device__ __forceinline__ us f2b(float f){
  union { float f; unsigned int u; } v; v.f = f;
  unsigned int u = v.u;
  unsigned int r = (u + 0x7FFFu + ((u >> 16) & 1u)) >> 16; // RNE
  return (us)r;
}
__device__ __forceinline__ unsigned int pack2(float a, float b){
  return (unsigned int)f2b(a) | ((unsigned int)f2b(b) << 16);
}
__device__ __forceinline__ float b2f(us h){
  union { unsigned int u; float f; } v; v.u = ((unsigned int)h) << 16;
  return v.f;
}
__device__ __forceinline__ float b2f_lo(unsigned int u){
  union { unsigned int x; float f; } v; v.x = u << 16; return v.f;
}
__device__ __forceinline__ float b2f_hi(unsigned int u){
  union { unsigned int x; float f; } v; v.x = u & 0xFFFF0000u; return v.f;
}

typedef __attribute__((address_space(1))) const unsigned int gas_u32;
typedef __attribute__((address_space(3))) unsigned int las_u32;
__device__ __forceinline__ void gl2lds16(const void* g, void* l){
  __builtin_amdgcn_global_load_lds((gas_u32*)g, (las_u32*)l, 16, 0, 0);
}

// ---------------- convert x (f32) -> xb (bf16)
__global__ __launch_bounds__(256) void convert_x(const float* __restrict__ x,
                                                 us* __restrict__ xb){
  size_t i = ((size_t)blockIdx.x * 256 + threadIdx.x) * 8;
  const float4* s = reinterpret_cast<const float4*>(x + i);
  float4 a = s[0], b = s[1];
  u32x4 w;
  w[0] = pack2(a.x, a.y); w[1] = pack2(a.z, a.w);
  w[2] = pack2(b.x, b.y); w[3] = pack2(b.z, b.w);
  *reinterpret_cast<u32x4*>(xb + i) = w;
}

// ---------------- prep: Wt1[n][k] = [wq|wk]^T (bf16), Wt2[n][k] = w_proj^T (bf16)
__global__ __launch_bounds__(256) void prep_w(const float* __restrict__ wq,
                                              const float* __restrict__ wk,
                                              const float* __restrict__ wp,
                                              us* __restrict__ wt1,
                                              us* __restrict__ wt2){
  int idx = blockIdx.x * 256 + threadIdx.x;
  const int tot1 = N1 * DDIM;
  if (idx < tot1){
    int n = idx / DDIM, k = idx % DDIM;
    float v = (n < DDIM) ? wq[k * DDIM + n] : wk[k * DDIM + (n - DDIM)];
    wt1[idx] = f2b(v);
  }
  int idx2 = idx - tot1;
  if (idx2 >= 0 && idx2 < DDIM * DDIM){
    int n = idx2 / DDIM, k = idx2 % DDIM;
    wt2[idx2] = f2b(wp[k * DDIM + n]);
  }
}

// ---------------- prep_wb: wbuf[b][n][d] = bf16( g[b][d] * w_proj[d][n] )
__global__ __launch_bounds__(256) void prep_wb(const us* __restrict__ wt2,
                                               const float* __restrict__ g,
                                               us* __restrict__ wbuf){
  size_t idx = (size_t)blockIdx.x * 256 + threadIdx.x;
  int d = (int)(idx % DDIM);
  size_t nd = idx / DDIM;
  int n = (int)(nd % DDIM);
  int b = (int)(nd / DDIM);
  float v = b2f(wt2[n * DDIM + d]) * g[(size_t)b * DDIM + d];
  wbuf[idx] = f2b(v);
}

// ---------------- ln_reduce: rstats from 3 col-block partials per row
__global__ __launch_bounds__(256) void ln_reduce(const float* __restrict__ lnS,
                                                 const float* __restrict__ lnQ,
                                                 float2* __restrict__ rstats){
  int r = blockIdx.x * 256 + threadIdx.x;
  float s = lnS[r] + lnS[MTOT + r] + lnS[2*MTOT + r];
  float q = lnQ[r] + lnQ[MTOT + r] + lnQ[2*MTOT + r];
  float mu = s * (1.0f / DDIM);
  float var = q * (1.0f / DDIM) - mu * mu;
  rstats[r] = make_float2(mu, rsqrtf(var + LNEPS));
}

// ================ 256x256 8-wave quadrant-phased pipelined GEMM core =========
// LDS (128 KB as us[65536]): A = 4 half-tile slots of [128][64] bf16 (16 KB each),
// B same at +32768 us. Ring slot for half h of K-tile kt: (2kt+h)&3.
// Phase order is SNAKE over C-quadrants: (qm,qn) = (0,0),(0,1),(1,1),(1,0).
// FRAGMENT REUSE (R4 lesson — LDS-read traffic was 2x and dominated MFMA):
// A-half fragments (8 b128) are read only at p0/p2 and reused by the next
// phase; B-half (4 b128) read each phase. 28 b128/wave/kt vs 48 before,
// with unchanged peak fragment registers (A overwritten in place at p2).
// Staging: kt in [1,10] stages kt+1's halves, one per phase (order A0,B0,B1,A1);
// kt0+kt1 staged in prologue. vmcnt(4) per phase (8 prologue; drain 2,0 at kt=11).
// First consumption per half (A0@p0, B0@p0, B1@p1, A1@p2) identical to the
// verified R4 schedule, so the drain analysis carries over. p3 re-uses B0 from
// registers; its slot (2kt)&3 is disjoint from kt's staged slots (2kt+2/3)&3.
// Bank swizzle: LDS[row][cell] = global[row][cell ^ (row&7)] (cell = 16B unit);
// ds_read de-swizzles with cell = ((kk<<2)|lh) ^ (lane&7).
__device__ __forceinline__ void gemm256_core(const us* __restrict__ Ag,
                                             const us* __restrict__ Bg,
                                             us* lds, int t,
                                             f32x4 (&acc)[4][4][2]){
  us* ldsA = lds;
  us* ldsB = lds + 32768;
  const int wave = t >> 6, lane = t & 63;
  const int wr = wave >> 2, wc = wave & 3, lr = lane & 15, lh = lane >> 4;
  const int srow = t >> 3;                  // 0..63
  const int scell = (t & 7) ^ ((t >> 3) & 7);
  const int key8 = lane & 7;                // == row&7 for all fragment rows

  auto stage = [&](int sel, int h, int kt){
    const us* gb = sel ? Bg : Ag;
    us* lb = sel ? ldsB : ldsA;
    int slot = (2*kt + h) & 3;
    #pragma unroll
    for (int j = 0; j < 2; ++j){
      const us* src = gb + (size_t)(h*128 + j*64 + srow) * DDIM + kt*64 + scell*8;
      gl2lds16(src, lb + slot*8192 + j*4096 + (wave << 9));
    }
  };

  // prologue: kt0 fully, kt1 fully (16 loads); kt0 guaranteed by vmcnt(8)
  stage(0,0,0); stage(1,0,0); stage(1,1,0); stage(0,1,0);
  stage(0,0,1); stage(1,0,1); stage(1,1,1); stage(0,1,1);
  asm volatile("s_waitcnt vmcnt(8)" ::: "memory");
  __builtin_amdgcn_s_barrier();

  bf16x8 av[4][2];   // current A-half fragments (refreshed at p0, p2)
  bf16x8 bv[2][2];   // current B-half fragments (refreshed every phase)

  for (int kt = 0; kt < 12; ++kt){
    #pragma unroll
    for (int p = 0; p < 4; ++p){
      // snake: (qm,qn) = (0,0),(0,1),(1,1),(1,0)
      const int qm = (p >> 1);
      const int qn = (p == 1 || p == 2) ? 1 : 0;
      const int q  = qm*2 + qn;            // acc index (epilogue layout unchanged)

      if (p == 0 || p == 2){               // refresh A-half qm
        const us* Ab = ldsA + ((2*kt + qm) & 3) * 8192;
        #pragma unroll
        for (int fm = 0; fm < 4; ++fm){
          int ra = wr*64 + fm*16 + lr;
          #pragma unroll
          for (int kk = 0; kk < 2; ++kk)
            av[fm][kk] = *reinterpret_cast<const bf16x8*>(
                &Ab[ra*64 + ((((kk<<2)|lh) ^ key8) << 3)]);
        }
      }
      {                                    // refresh B-half qn
        const us* Bb = ldsB + ((2*kt + qn) & 3) * 8192;
        #pragma unroll
        for (int fn = 0; fn < 2; ++fn){
          int rb = wc*32 + fn*16 + lr;
          #pragma unroll
          for (int kk = 0; kk < 2; ++kk)
            bv[fn][kk] = *reinterpret_cast<const bf16x8*>(
                &Bb[rb*64 + ((((kk<<2)|lh) ^ key8) << 3)]);
        }
      }
      if (kt >= 1 && kt <= 10){
        if      (p == 0) stage(0, 0, kt+1);
        else if (p == 1) stage(1, 0, kt+1);
        else if (p == 2) stage(1, 1, kt+1);
        else             stage(0, 1, kt+1);
      }
      __builtin_amdgcn_sched_barrier(0);
      __builtin_amdgcn_s_barrier();
      __builtin_amdgcn_s_setprio(1);
      #pragma unroll
      for (int fm = 0; fm < 4; ++fm)
        #pragma unroll
        for (int fn = 0; fn < 2; ++fn)
          #pragma unroll
          for (int kk = 0; kk < 2; ++kk)
            acc[q][fm][fn] = __builtin_amdgcn_mfma_f32_16x16x32_bf16(
                av[fm][kk], bv[fn][kk], acc[q][fm][fn], 0, 0, 0);
      __builtin_amdgcn_s_setprio(0);
      if (kt < 11)      { asm volatile("s_waitcnt vmcnt(4)" ::: "memory"); }
      else if (p == 0)  { asm volatile("s_waitcnt vmcnt(2)" ::: "memory"); }
      else if (p == 1)  { asm volatile("s_waitcnt vmcnt(0)" ::: "memory"); }
      __builtin_amdgcn_sched_barrier(0);
      __builtin_amdgcn_s_barrier();
    }
  }
}

// ---------------- GEMM1: [q|k] = xb @ wt1^T + bias
__global__ __launch_bounds__(512, 2) void gemm_qk(
    const us* __restrict__ xb, const us* __restrict__ wt1,
    const float* __restrict__ bq, const float* __restrict__ bk,
    const float* __restrict__ w_g,
    us* __restrict__ kout,
    float* __restrict__ qwp, float* __restrict__ qsp, float* __restrict__ ksp,
    float* __restrict__ lnS, float* __restrict__ lnQ)
{
  extern __shared__ us lds[];
  int bid = blockIdx.x;
  int swz = (bid & 7) * ((int)gridDim.x >> 3) + (bid >> 3);
  int bn = swz % 6, bm = swz / 6;       // n fastest: A-panel shared per XCD chunk
  int m0 = bm * 256, n0 = bn * 256;
  int t = threadIdx.x;

  f32x4 acc[4][4][2] = {};
  gemm256_core(xb + (size_t)m0 * DDIM, wt1 + (size_t)n0 * DDIM, lds, t, acc);

  int wave = t >> 6, lane = t & 63;
  int wr = wave >> 2, wc = wave & 3, lr = lane & 15, lh = lane >> 4;
  bool is_q = (n0 < DDIM);
  int b = m0 >> 12, mc = (m0 & (NP-1)) >> 8;

  float bias[2][2];
  #pragma unroll
  for (int qn = 0; qn < 2; ++qn)
    #pragma unroll
    for (int fn = 0; fn < 2; ++fn){
      int col = qn*128 + wc*32 + fn*16 + lr;
      bias[qn][fn] = is_q ? bq[n0 + col] : bk[n0 - DDIM + col];
    }

  // write 256x256 bf16 tile to LDS (bank-swizzled)
  #pragma unroll
  for (int p = 0; p < 4; ++p){
    int qm = p >> 1, qn = p & 1;
    #pragma unroll
    for (int fm = 0; fm < 4; ++fm)
      #pragma unroll
      for (int r = 0; r < 4; ++r){
        int row = qm*128 + wr*64 + fm*16 + lh*4 + r;
        #pragma unroll
        for (int fn = 0; fn < 2; ++fn){
          int col = qn*128 + wc*32 + fn*16 + lr;
          lds[row*256 + (col ^ ((row & 7) << 3))] = f2b(acc[p][fm][fn][r] + bias[qn][fn]);
        }
      }
  }
  __syncthreads();

  // sweep: coalesced k-store + column partials (+row LN partials for k-blocks)
  int c8 = t & 31, rb = t >> 5;
  float cp[8] = {0,0,0,0,0,0,0,0};
  float cpw[8] = {0,0,0,0,0,0,0,0};
  float rs16[16], rq16[16];
  #pragma unroll
  for (int s = 0; s < 16; ++s){
    int row = s*16 + rb;
    u32x4 ch = *reinterpret_cast<const u32x4*>(&lds[row*256 + ((c8 ^ (row & 7)) << 3)]);
    float v[8];
    #pragma unroll
    for (int i = 0; i < 4; ++i){ v[2*i] = b2f_lo(ch[i]); v[2*i+1] = b2f_hi(ch[i]); }
    if (is_q){
      float wg = w_g[(m0 & (NP-1)) + row];
      #pragma unroll
      for (int j = 0; j < 8; ++j){ cp[j] += v[j]; cpw[j] += wg * v[j]; }
    } else {
      *reinterpret_cast<u32x4*>(kout + (size_t)(m0+row)*DDIM + (n0 - DDIM) + c8*8) = ch;
      float ss = 0.f, qq = 0.f;
      #pragma unroll
      for (int j = 0; j < 8; ++j){ cp[j] += v[j]; ss += v[j]; qq += v[j]*v[j]; }
      rs16[s] = ss; rq16[s] = qq;
    }
  }
  __syncthreads();
  float* colP  = reinterpret_cast<float*>(lds);   // [256][16]
  float* colPw = colP + 4096;                     // [256][16] (q)
  float* rowP  = colP + 8192;                     // [256][32] (k)
  float* rowQ  = colP + 16384;                    // [256][32] (k)
  #pragma unroll
  for (int j = 0; j < 8; ++j){
    colP[(c8*8+j)*16 + rb] = cp[j];
    if (is_q) colPw[(c8*8+j)*16 + rb] = cpw[j];
  }
  if (!is_q){
    #pragma unroll
    for (int s = 0; s < 16; ++s){
      int row = s*16 + rb;
      rowP[row*32 + c8] = rs16[s];
      rowQ[row*32 + c8] = rq16[s];
    }
  }
  __syncthreads();
  if (t < 256){
    float s0 = 0.f;
    #pragma unroll
    for (int i = 0; i < 16; ++i) s0 += colP[t*16 + i];
    size_t base = ((size_t)b * 16 + mc) * DDIM;
    if (is_q){
      float s1 = 0.f;
      #pragma unroll
      for (int i = 0; i < 16; ++i) s1 += colPw[t*16 + i];
      qwp[base + n0 + t] = s1;
      qsp[base + n0 + t] = s0;
    } else {
      ksp[base + (n0 - DDIM) + t] = s0;
      float rs_ = 0.f, rq_ = 0.f;
      #pragma unroll
      for (int i = 0; i < 32; ++i){ rs_ += rowP[t*32 + i]; rq_ += rowQ[t*32 + i]; }
      int kb = bn - 3;
      lnS[(size_t)kb * MTOT + m0 + t] = rs_;
      lnQ[(size_t)kb * MTOT + m0 + t] = rq_;
    }
  }
}

// ---------------- combine: per batch — softmax over d, gating chain, g
__global__ __launch_bounds__(256) void combine(
    const float* __restrict__ qwp, const float* __restrict__ qsp, const float* __restrict__ ksp,
    const float* __restrict__ w_fc, const float* __restrict__ b_fc,
    const float* __restrict__ w_fc2, const float* __restrict__ b_fc2,
    float* __restrict__ g)
{
  __shared__ float smA[DDIM];
  __shared__ float smQM[DDIM];
  __shared__ float smKS[DDIM];
  __shared__ float tmat[12][DDIM];
  __shared__ float red[256];
  __shared__ float wbar[12];
  __shared__ float bbar;
  int b = blockIdx.x, t = threadIdx.x;

  for (int col = t; col < DDIM; col += 256){
    float s0 = 0.f, s1 = 0.f, s2 = 0.f;
    for (int mc = 0; mc < 16; ++mc){
      size_t base = ((size_t)b * 16 + mc) * DDIM + col;
      s0 += qwp[base]; s1 += qsp[base]; s2 += ksp[base];
    }
    smA[col] = s0 * SCALEF;
    smQM[col] = s1 * (1.0f / NP);
    smKS[col] = s2;
  }
  __syncthreads();
  float lmax = -1e30f;
  for (int col = t; col < DDIM; col += 256) lmax = fmaxf(lmax, smA[col]);
  red[t] = lmax; __syncthreads();
  for (int off = 128; off; off >>= 1){
    if (t < off) red[t] = fmaxf(red[t], red[t + off]);
    __syncthreads();
  }
  float mx = red[0];
  __syncthreads();
  float lsum = 0.f;
  for (int col = t; col < DDIM; col += 256){
    float e = __expf(smA[col] - mx);
    smA[col] = e; lsum += e;
  }
  red[t] = lsum; __syncthreads();
  for (int off = 128; off; off >>= 1){
    if (t < off) red[t] += red[t + off];
    __syncthreads();
  }
  float inv = 1.0f / red[0];
  for (int col = t; col < DDIM; col += 256) smA[col] *= inv;

  if (t < 12){
    float s = 0.f;
    for (int j = 0; j < 12; ++j) s += w_fc2[t * 12 + j];
    wbar[t] = s * (1.0f / 12.0f);
  }
  if (t == 12){
    float s = 0.f;
    for (int j = 0; j < 12; ++j) s += b_fc2[j];
    bbar = s * (1.0f / 12.0f);
  }
  __syncthreads();
  for (int idx = t; idx < 12 * DDIM; idx += 256){
    int h = idx / DDIM, j = idx % DDIM;
    float s = b_fc[j];
    const float* qm = &smQM[h * 64];
    #pragma unroll 4
    for (int i = 0; i < 64; ++i) s += qm[i] * w_fc[i * DDIM + j];
    tmat[h][j] = 0.5f * s * (1.0f + erff(s * 0.70710678118654752f));
  }
  __syncthreads();
  for (int p = t; p < DDIM; p += 256){
    float s = bbar;
    #pragma unroll
    for (int m = 0; m < 12; ++m){
      int f = p * 12 + m;                 // torch reshape (b,12,768)->(b,768,12)
      s += tmat[f / DDIM][f % DDIM] * wbar[m];
    }
    float dv = 1.0f / (1.0f + __expf(-s));
    g[(size_t)b * DDIM + p] = smA[p] * smKS[p] * dv;
  }
}

// ---------------- GEMM2: out = k @ (g-scaled w_proj) + b_proj + layernorm(k)
__global__ __launch_bounds__(512, 2) void gemm_out(
    const us* __restrict__ kin, const us* __restrict__ wbuf,
    const float2* __restrict__ rstats,
    const float* __restrict__ bp, const float* __restrict__ gamma,
    const float* __restrict__ beta,
    float* __restrict__ out)
{
  extern __shared__ us lds[];
  int bid = blockIdx.x;
  int swz = (bid & 7) * ((int)gridDim.x >> 3) + (bid >> 3);
  int bn = swz % 3, bm = swz / 3;
  int m0 = bm * 256, n0 = bn * 256;
  int t = threadIdx.x;
  int b = m0 >> 12;

  f32x4 acc[4][4][2] = {};
  gemm256_core(kin + (size_t)m0 * DDIM,
               wbuf + (size_t)b * DDIM * DDIM + (size_t)n0 * DDIM, lds, t, acc);

  int wave = t >> 6, lane = t & 63;
  int wr = wave >> 2, wc = wave & 3, lr = lane & 15, lh = lane >> 4;

  // stage kin 256x256 tile (swizzled source cells, linear LDS dest)
  #pragma unroll
  for (int j = 0; j < 16; ++j){
    int row = j*16 + (t >> 5);
    const us* src = kin + (size_t)(m0 + row) * DDIM + n0 + (((t & 31) ^ (row & 7)) << 3);
    gl2lds16(src, lds + j*4096 + (wave << 9));
  }
  asm volatile("s_waitcnt vmcnt(0)" ::: "memory");
  __syncthreads();

  // fold bias + layernorm(k) into acc
  #pragma unroll
  for (int p = 0; p < 4; ++p){
    int qm = p >> 1, qn = p & 1;
    #pragma unroll
    for (int fn = 0; fn < 2; ++fn){
      int col = qn*128 + wc*32 + fn*16 + lr;
      float bpv = bp[n0 + col], gmv = gamma[n0 + col], btv = beta[n0 + col];
      #pragma unroll
      for (int fm = 0; fm < 4; ++fm)
        #pragma unroll
        for (int r = 0; r < 4; ++r){
          int row = qm*128 + wr*64 + fm*16 + lh*4 + r;
          float2 st = rstats[m0 + row];
          float kv = b2f(lds[row*256 + (col ^ ((row & 7) << 3))]);
          acc[p][fm][fn][r] += bpv + (kv - st.x) * st.y * gmv + btv;
        }
    }
  }
  __syncthreads();

  // two half-passes: relayout f32 through LDS, float4 stores
  float* fb = reinterpret_cast<float*>(lds);   // [256][128] f32 = 128 KB
  #pragma unroll
  for (int h = 0; h < 2; ++h){
    #pragma unroll
    for (int qm2 = 0; qm2 < 2; ++qm2){
      int p = qm2*2 + h;   // phases with qn == h
      #pragma unroll
      for (int fm = 0; fm < 4; ++fm)
        #pragma unroll
        for (int r = 0; r < 4; ++r){
          int row = qm2*128 + wr*64 + fm*16 + lh*4 + r;
          #pragma unroll
          for (int fn = 0; fn < 2; ++fn){
            int c = wc*32 + fn*16 + lr;
            fb[row*128 + (c ^ ((row & 7) << 2))] = acc[p][fm][fn][r];
          }
        }
    }
    __syncthreads();
    #pragma unroll
    for (int s = 0; s < 16; ++s){
      int u = s*512 + t;
      int row = u >> 5, c4 = u & 31;
      float4 vv = *reinterpret_cast<const float4*>(&fb[row*128 + ((c4 ^ (row & 7)) << 2)]);
      *reinterpret_cast<float4*>(&out[(size_t)(m0 + row) * DDIM + n0 + h*128 + c4*4]) = vv;
    }
    __syncthreads();
  }
}

extern "C" void kernel_launch(void* const* d_in, const int* in_sizes, int n_in,
                              void* d_out, int out_size, void* d_ws, size_t ws_size,
                              hipStream_t stream)
{
  const float* x      = (const float*)d_in[0];
  const float* wq     = (const float*)d_in[1];
  const float* bq     = (const float*)d_in[2];
  const float* wk     = (const float*)d_in[3];
  const float* bk     = (const float*)d_in[4];
  const float* w_g    = (const float*)d_in[5];
  const float* w_fc   = (const float*)d_in[6];
  const float* b_fc   = (const float*)d_in[7];
  const float* w_fc2  = (const float*)d_in[8];
  const float* b_fc2  = (const float*)d_in[9];
  const float* w_proj = (const float*)d_in[10];
  const float* b_proj = (const float*)d_in[11];
  const float* gamma  = (const float*)d_in[12];
  const float* beta   = (const float*)d_in[13];
  float* out = (float*)d_out;

  char* ws = (char*)d_ws;
  us*     xb    = (us*)(ws);                       // 100,663,296 B
  us*     kbuf  = (us*)(ws + 100663296);           // 100,663,296 B
  us*     wt1   = (us*)(ws + 201326592);           //   2,359,296 B
  us*     wt2   = (us*)(ws + 203685888);           //   1,179,648 B
  us*     wbuf  = (us*)(ws + 204865536);           //  18,874,368 B
  float*  qwp   = (float*)(ws + 223739904);        //     786,432 B
  float*  qsp   = (float*)(ws + 224526336);        //     786,432 B
  float*  ksp   = (float*)(ws + 225312768);        //     786,432 B
  float*  lnS   = (float*)(ws + 226099200);        //     786,432 B
  float*  lnQ   = (float*)(ws + 226885632);        //     786,432 B
  float*  g     = (float*)(ws + 227672064);        //      49,152 B
  float2* rstat = (float2*)(ws + 227721216);       //     524,288 B  (~217.7 MiB total)

  convert_x<<<dim3(MTOT * DDIM / (256 * 8)), dim3(256), 0, stream>>>(x, xb);
  prep_w<<<dim3((N1 * DDIM + DDIM * DDIM) / 256), dim3(256), 0, stream>>>(wq, wk, w_proj, wt1, wt2);
  gemm_qk<<<dim3((MTOT / 256) * (N1 / 256)), dim3(512), 131072, stream>>>(
      xb, wt1, bq, bk, w_g, kbuf, qwp, qsp, ksp, lnS, lnQ);
  ln_reduce<<<dim3(MTOT / 256), dim3(256), 0, stream>>>(lnS, lnQ, rstat);
  combine<<<dim3(NB), dim3(256), 0, stream>>>(qwp, qsp, ksp, w_fc, b_fc, w_fc2, b_fc2, g);
  prep_wb<<<dim3(NB * DDIM * DDIM / 256), dim3(256), 0, stream>>>(wt2, g, wbuf);
  gemm_out<<<dim3((MTOT / 256) * (DDIM / 256)), dim3(512), 131072, stream>>>(
      kbuf, wbuf, rstat, b_proj, gamma, beta, out);
}